// Round 6
// baseline (379.951 us; speedup 1.0000x reference)
//
#include <hip/hip_runtime.h>
#include <math.h>

#define Lc 13
#define Hc 1024
#define Bc 32
#define Sc 2048
#define BSc (Bc*Sc)
#define CHUNK 128
#define NCHUNK 16
#define NBLK (Bc*NCHUNK)   // 512 chunk blocks

#define INV_LN2 1.44269504088896340736f
#define LN2f    0.69314718055994530942f

#if __has_builtin(__builtin_amdgcn_exp2f)
#define EXP2F(x) __builtin_amdgcn_exp2f(x)
#else
#define EXP2F(x) exp2f(x)
#endif
#if __has_builtin(__builtin_amdgcn_logf)
#define LOG2F(x) __builtin_amdgcn_logf(x)
#else
#define LOG2F(x) log2f(x)
#endif

// DPP-based partial butterfly: v += lane-permuted v (VALU only, no LDS).
// CTRL must be a compile-time constant -> template parameter.
template <int CTRL>
__device__ __forceinline__ float dpp_add(float v) {
  int p = __builtin_amdgcn_update_dpp(0, __float_as_int(v), CTRL, 0xF, 0xF, true);
  return v + __int_as_float(p);
}

// ---------------------------------------------------------------------------
// Kernel A: logits = hs @ W^T + b, barrier-free streaming.
// W staged once in LDS (53 KB). Each wave independent: 8 rows, 2 rows/iter.
// Lane ln owns h in {ln*4 + k*256}: A loads = 4x contiguous 1KB dwordx4/row;
// W ds_read_b128 contiguous (conflict-free). 26 partials reduced per iter:
// xor1/2/4/8 via DPP (quad_perm, half/row mirror), xor16/32 via shfl.
// Store: cndmask-select (no dynamic index), lanes 0..25 -> 26 contiguous f32.
// ---------------------------------------------------------------------------
__global__ __launch_bounds__(512, 4)
void k_logits(const float* __restrict__ A, const float* __restrict__ W,
              const float* __restrict__ bias, float* __restrict__ out) {
  __shared__ float Wl[Lc * Hc];   // 53.2 KB
  const int tid = threadIdx.x;

  { // stage W once, coalesced float4
    const float4* Wg4 = (const float4*)W;
    float4* Wl4 = (float4*)Wl;
#pragma unroll
    for (int i = 0; i < 7; ++i) {
      int idx = tid + i * 512;
      if (idx < Lc * (Hc / 4)) Wl4[idx] = Wg4[idx];
    }
  }
  __syncthreads();

  const int ln = tid & 63;
  const int wv = tid >> 6;                       // 0..7
  const size_t rowBase = (size_t)blockIdx.x * 64 + (size_t)wv * 8;

  float b[Lc];
#pragma unroll
  for (int l = 0; l < Lc; ++l) b[l] = bias[l];   // uniform -> SGPR

  for (int it = 0; it < 4; ++it) {
    const size_t r0 = rowBase + (size_t)it * 2;
    const float* A0 = A + r0 * Hc + ln * 4;
    const float* A1 = A0 + Hc;
    float4 a0[4], a1[4];
#pragma unroll
    for (int k = 0; k < 4; ++k) {
      a0[k] = *(const float4*)(A0 + k * 256);
      a1[k] = *(const float4*)(A1 + k * 256);
    }
    float acc0[Lc], acc1[Lc];
#pragma unroll
    for (int l = 0; l < Lc; ++l) { acc0[l] = 0.f; acc1[l] = 0.f; }
#pragma unroll
    for (int l = 0; l < Lc; ++l) {
#pragma unroll
      for (int k = 0; k < 4; ++k) {
        float4 w = *(const float4*)&Wl[l * Hc + k * 256 + ln * 4];
        acc0[l] = fmaf(a0[k].x, w.x, acc0[l]); acc0[l] = fmaf(a0[k].y, w.y, acc0[l]);
        acc0[l] = fmaf(a0[k].z, w.z, acc0[l]); acc0[l] = fmaf(a0[k].w, w.w, acc0[l]);
        acc1[l] = fmaf(a1[k].x, w.x, acc1[l]); acc1[l] = fmaf(a1[k].y, w.y, acc1[l]);
        acc1[l] = fmaf(a1[k].z, w.z, acc1[l]); acc1[l] = fmaf(a1[k].w, w.w, acc1[l]);
      }
    }
    // 64-lane butterfly on 26 values.
    // quad_perm(1,0,3,2)=0xB1 (xor1); quad_perm(2,3,0,1)=0x4E (xor2);
    // row_half_mirror=0x141 (i^7: == xor4 after xor1/2); row_mirror=0x140 (i^15).
#pragma unroll
    for (int l = 0; l < Lc; ++l) {
      float s0 = acc0[l], s1 = acc1[l];
      s0 = dpp_add<0xB1>(s0);  s1 = dpp_add<0xB1>(s1);
      s0 = dpp_add<0x4E>(s0);  s1 = dpp_add<0x4E>(s1);
      s0 = dpp_add<0x141>(s0); s1 = dpp_add<0x141>(s1);
      s0 = dpp_add<0x140>(s0); s1 = dpp_add<0x140>(s1);
      s0 += __shfl_xor(s0, 16, 64); s1 += __shfl_xor(s1, 16, 64);
      s0 += __shfl_xor(s0, 32, 64); s1 += __shfl_xor(s1, 32, 64);
      acc0[l] = s0; acc1[l] = s1;
    }
    float ov = 0.f;
#pragma unroll
    for (int l = 0; l < Lc; ++l) {
      ov = (ln == l)      ? acc0[l] + b[l] : ov;
      ov = (ln == Lc + l) ? acc1[l] + b[l] : ov;
    }
    if (ln < 2 * Lc) out[r0 * Lc + ln] = ov;
  }
}

// ---------------------------------------------------------------------------
// Kernel B: per (batch, chunk) 13x13 transfer matrix, LINEAR domain
// (13 shfl + 13 fma + 1 exp2 per step; exponent-extract renorm every 8).
// Wave 0 also computes the chunk's numerator partial. Block 0 zeroes out0.
// ---------------------------------------------------------------------------
__global__ void k_chunks(const float* __restrict__ logits, const int* __restrict__ mask,
                         const int* __restrict__ labels, const float* __restrict__ T,
                         float* __restrict__ Mout, float* __restrict__ numpart,
                         float* __restrict__ cntpart, float* __restrict__ out0) {
  const int bp = blockIdx.x;
  const int b  = bp >> 4;       // NCHUNK == 16
  const int p  = bp & 15;
  const int tid = threadIdx.x;
  if (bp == 0 && tid == 0) out0[0] = 0.f;   // zero loss accumulator for k_final
  const int g = tid >> 4;
  const int k = tid & 15;
  const int kk = (k < 13) ? k : 0;
  const int gg = (g < 13) ? g : 0;
  const bool active = (g < 13) && (k < 13);
  const size_t lbase = (size_t)b * Sc;
  const int t0 = 1 + p * CHUNK;
  const int t1 = min(t0 + CHUNK, Sc);

  float U[13];   // column kk of exp(T)
#pragma unroll
  for (int j = 0; j < 13; ++j) U[j] = EXP2F(T[j * 13 + kk] * INV_LN2);

  float e0 = logits[(lbase + t0) * Lc + kk] * INV_LN2;
  int   m0 = mask[lbase + t0];
  float P = m0 ? EXP2F(T[gg * 13 + kk] * INV_LN2 + e0) : ((g == k) ? 1.f : 0.f);
  float off = 0.f;

  for (int t = t0 + 1; t < t1; ++t) {
    float e2 = logits[(lbase + t) * Lc + kk] * INV_LN2;
    int   mk = mask[lbase + t];
    float pj[13];
#pragma unroll
    for (int j = 0; j < 13; ++j) pj[j] = __shfl(P, j, 16);
    float s0 = pj[0] * U[0];  s0 = fmaf(pj[4],  U[4],  s0);
    s0 = fmaf(pj[8],  U[8],  s0);  s0 = fmaf(pj[12], U[12], s0);
    float s1 = pj[1] * U[1];  s1 = fmaf(pj[5],  U[5],  s1);  s1 = fmaf(pj[9],  U[9],  s1);
    float s2 = pj[2] * U[2];  s2 = fmaf(pj[6],  U[6],  s2);  s2 = fmaf(pj[10], U[10], s2);
    float s3 = pj[3] * U[3];  s3 = fmaf(pj[7],  U[7],  s3);  s3 = fmaf(pj[11], U[11], s3);
    float s = (s0 + s1) + (s2 + s3);
    float Pn = EXP2F(e2) * s;
    P = mk ? Pn : P;
    if (((t - t0) & 7) == 0) {   // renorm: keep row max in [1,2)
      float mx = P;
#pragma unroll
      for (int o = 1; o < 16; o <<= 1) mx = fmaxf(mx, __shfl_xor(mx, o, 16));
      unsigned eb = (__float_as_uint(mx) >> 23) & 255u;
      float scale = __uint_as_float((254u - eb) << 23);   // 2^(127-eb)
      P *= scale;
      off += (float)((int)eb - 127);
    }
  }
  if (active) Mout[(size_t)bp * 169 + g * 13 + k] = (P > 0.f) ? (LOG2F(P) + off) : -1e30f;

  // ---- numerator partial for this chunk's tokens [t0, t1) ----
  if (tid < 64) {
    float np = 0.f; int cnt = 0;
    for (int t = t0 + tid; t < t1; t += 64) {
      int mk = mask[lbase + t];
      if (mk) {
        int tg = labels[lbase + t];
        int pg = labels[lbase + t - 1];
        np += T[pg * 13 + tg] + logits[(lbase + t) * Lc + tg];
        cnt += 1;
      }
    }
#pragma unroll
    for (int o = 1; o < 64; o <<= 1) {
      np  += __shfl_xor(np, o, 64);
      cnt += __shfl_xor(cnt, o, 64);
    }
    if (tid == 0) { numpart[bp] = np; cntpart[bp] = (float)cnt; }
  }
}

// ---------------------------------------------------------------------------
// Kernel C: per batch: combine 16 chunk matrices (log2 domain) -> denominator;
// assemble numerator from partials; atomicAdd loss.
// ---------------------------------------------------------------------------
__global__ void k_final(const float* __restrict__ logits, const int* __restrict__ mask,
                        const int* __restrict__ labels, const float* __restrict__ startT,
                        const float* __restrict__ endT, const float* __restrict__ Mws,
                        const float* __restrict__ numpart, const float* __restrict__ cntpart,
                        float* __restrict__ out0) {
  const int b = blockIdx.x;
  const int lane = threadIdx.x;
  const int kk = (lane < 13) ? lane : 0;
  const size_t lbase = (size_t)b * Sc;

  // ---- denominator (log2 domain) ----
  float v = (startT[kk] + logits[lbase * Lc + kk]) * INV_LN2;
  for (int p = 0; p < NCHUNK; ++p) {
    const float* Mp = Mws + (size_t)(b * NCHUNK + p) * 169;
    float a[13];
#pragma unroll
    for (int j = 0; j < 13; ++j) a[j] = __shfl(v, j, 64) + Mp[j * 13 + kk];
    float mx = a[0];
#pragma unroll
    for (int j = 1; j < 13; ++j) mx = fmaxf(mx, a[j]);
    float s = 0.f;
#pragma unroll
    for (int j = 0; j < 13; ++j) s += EXP2F(a[j] - mx);
    v = mx + LOG2F(s);
  }
  float x = (lane < 13) ? (v + endT[kk] * INV_LN2) : -1e30f;
  float mx = x;
#pragma unroll
  for (int off = 1; off < 16; off <<= 1) mx = fmaxf(mx, __shfl_xor(mx, off, 16));
  float sx = EXP2F(x - mx);
#pragma unroll
  for (int off = 1; off < 16; off <<= 1) sx += __shfl_xor(sx, off, 16);
  float den = (mx + LOG2F(sx)) * LN2f;   // valid on lanes 0..15

  // ---- numerator from chunk partials (lanes 0..15) ----
  float np = 0.f, cs = 0.f;
  if (lane < NCHUNK) { np = numpart[b * NCHUNK + lane]; cs = cntpart[b * NCHUNK + lane]; }
#pragma unroll
  for (int o = 1; o < 16; o <<= 1) {
    np += __shfl_xor(np, o, 16);
    cs += __shfl_xor(cs, o, 16);
  }
  if (lane == 0) {
    int lab0 = labels[lbase];
    int seqlen = mask[lbase] + (int)(cs + 0.5f);
    int lastTag = labels[lbase + seqlen - 1];
    float num = startT[lab0] + logits[lbase * Lc + lab0] + np + endT[lastTag];
    float llh = num - den;
    atomicAdd(out0, -llh * (1.0f / Bc));
  }
}

extern "C" void kernel_launch(void* const* d_in, const int* in_sizes, int n_in,
                              void* d_out, int out_size, void* d_ws, size_t ws_size,
                              hipStream_t stream) {
  const float* hs     = (const float*)d_in[0];
  const int*   amask  = (const int*)d_in[1];
  const int*   labels = (const int*)d_in[2];
  const float* W      = (const float*)d_in[3];
  const float* bias   = (const float*)d_in[4];
  const float* startT = (const float*)d_in[5];
  const float* endT   = (const float*)d_in[6];
  const float* T      = (const float*)d_in[7];

  float* out    = (float*)d_out;
  float* logits = out + 1;            // output 1 follows the scalar loss
  float* Mws    = (float*)d_ws;       // 512*169 floats = 346 KB
  float* numpart = Mws + (size_t)NBLK * 169;
  float* cntpart = numpart + NBLK;    // total ~350 KB of ws

  k_logits<<<BSc / 64, 512, 0, stream>>>(hs, W, bias, logits);
  k_chunks<<<NBLK, 256, 0, stream>>>(logits, amask, labels, T, Mws, numpart, cntpart, out);
  k_final <<<Bc, 64, 0, stream>>>(logits, amask, labels, startT, endT, Mws, numpart, cntpart, out);
}

// Round 7
// 172.919 us; speedup vs baseline: 2.1973x; 2.1973x over previous
//
#include <hip/hip_runtime.h>
#include <math.h>

#define Lc 13
#define Hc 1024
#define Bc 32
#define Sc 2048
#define BSc (Bc*Sc)
#define CHUNK 128
#define NCHUNK 16
#define NBLK (Bc*NCHUNK)   // 512 chunk blocks

#define INV_LN2 1.44269504088896340736f
#define LN2f    0.69314718055994530942f

#if __has_builtin(__builtin_amdgcn_exp2f)
#define EXP2F(x) __builtin_amdgcn_exp2f(x)
#else
#define EXP2F(x) exp2f(x)
#endif
#if __has_builtin(__builtin_amdgcn_logf)
#define LOG2F(x) __builtin_amdgcn_logf(x)
#else
#define LOG2F(x) log2f(x)
#endif

// DPP-based partial butterfly: v += lane-permuted v (VALU only, no LDS).
// CTRL must be a compile-time constant -> template parameter.
template <int CTRL>
__device__ __forceinline__ float dpp_add(float v) {
  int p = __builtin_amdgcn_update_dpp(0, __float_as_int(v), CTRL, 0xF, 0xF, true);
  return v + __int_as_float(p);
}

// ---------------------------------------------------------------------------
// Kernel A: logits = hs @ W^T + b, barrier-free streaming.
// W staged once in LDS (53 KB). Each wave independent: 8 rows, 2 rows/iter.
// Lane ln owns h in {ln*4 + k*256}: A loads = 4x contiguous 1KB dwordx4/row;
// W ds_read_b128 contiguous (conflict-free). 26 partials reduced per iter:
// xor1/2/4/8 via DPP, xor16/32 via shfl. Store: cndmask-select, 26 f32/iter.
// __launch_bounds__(512,2): 128-VGPR budget -- (512,4) capped VGPRs at 64 and
// SPILLED (R6: FETCH 802MB/WRITE 356MB scratch traffic, 3x ideal bytes).
// LDS 53KB limits to 2 blocks/CU regardless, so occupancy is unchanged.
// ---------------------------------------------------------------------------
__global__ __launch_bounds__(512, 2)
void k_logits(const float* __restrict__ A, const float* __restrict__ W,
              const float* __restrict__ bias, float* __restrict__ out) {
  __shared__ float Wl[Lc * Hc];   // 53.2 KB
  const int tid = threadIdx.x;

  { // stage W once, coalesced float4
    const float4* Wg4 = (const float4*)W;
    float4* Wl4 = (float4*)Wl;
#pragma unroll
    for (int i = 0; i < 7; ++i) {
      int idx = tid + i * 512;
      if (idx < Lc * (Hc / 4)) Wl4[idx] = Wg4[idx];
    }
  }
  __syncthreads();

  const int ln = tid & 63;
  const int wv = tid >> 6;                       // 0..7
  const size_t rowBase = (size_t)blockIdx.x * 64 + (size_t)wv * 8;

  float b[Lc];
#pragma unroll
  for (int l = 0; l < Lc; ++l) b[l] = bias[l];   // uniform -> SGPR

  for (int it = 0; it < 4; ++it) {
    const size_t r0 = rowBase + (size_t)it * 2;
    const float* A0 = A + r0 * Hc + ln * 4;
    const float* A1 = A0 + Hc;
    float4 a0[4], a1[4];
#pragma unroll
    for (int k = 0; k < 4; ++k) {
      a0[k] = *(const float4*)(A0 + k * 256);
      a1[k] = *(const float4*)(A1 + k * 256);
    }
    float acc0[Lc], acc1[Lc];
#pragma unroll
    for (int l = 0; l < Lc; ++l) { acc0[l] = 0.f; acc1[l] = 0.f; }
#pragma unroll
    for (int l = 0; l < Lc; ++l) {
#pragma unroll
      for (int k = 0; k < 4; ++k) {
        float4 w = *(const float4*)&Wl[l * Hc + k * 256 + ln * 4];
        acc0[l] = fmaf(a0[k].x, w.x, acc0[l]); acc0[l] = fmaf(a0[k].y, w.y, acc0[l]);
        acc0[l] = fmaf(a0[k].z, w.z, acc0[l]); acc0[l] = fmaf(a0[k].w, w.w, acc0[l]);
        acc1[l] = fmaf(a1[k].x, w.x, acc1[l]); acc1[l] = fmaf(a1[k].y, w.y, acc1[l]);
        acc1[l] = fmaf(a1[k].z, w.z, acc1[l]); acc1[l] = fmaf(a1[k].w, w.w, acc1[l]);
      }
    }
    // 64-lane butterfly on 26 values.
    // quad_perm(1,0,3,2)=0xB1 (xor1); quad_perm(2,3,0,1)=0x4E (xor2);
    // row_half_mirror=0x141 (i^7); row_mirror=0x140 (i^15).
#pragma unroll
    for (int l = 0; l < Lc; ++l) {
      float s0 = acc0[l], s1 = acc1[l];
      s0 = dpp_add<0xB1>(s0);  s1 = dpp_add<0xB1>(s1);
      s0 = dpp_add<0x4E>(s0);  s1 = dpp_add<0x4E>(s1);
      s0 = dpp_add<0x141>(s0); s1 = dpp_add<0x141>(s1);
      s0 = dpp_add<0x140>(s0); s1 = dpp_add<0x140>(s1);
      s0 += __shfl_xor(s0, 16, 64); s1 += __shfl_xor(s1, 16, 64);
      s0 += __shfl_xor(s0, 32, 64); s1 += __shfl_xor(s1, 32, 64);
      acc0[l] = s0; acc1[l] = s1;
    }
    float ov = 0.f;
#pragma unroll
    for (int l = 0; l < Lc; ++l) {
      ov = (ln == l)      ? acc0[l] + b[l] : ov;
      ov = (ln == Lc + l) ? acc1[l] + b[l] : ov;
    }
    if (ln < 2 * Lc) out[r0 * Lc + ln] = ov;
  }
}

// ---------------------------------------------------------------------------
// Kernel B: per (batch, chunk) 13x13 transfer matrix, LINEAR domain
// (13 shfl + 13 fma + 1 exp2 per step; exponent-extract renorm every 8).
// Wave 0 also computes the chunk's numerator partial. Block 0 zeroes out0.
// ---------------------------------------------------------------------------
__global__ void k_chunks(const float* __restrict__ logits, const int* __restrict__ mask,
                         const int* __restrict__ labels, const float* __restrict__ T,
                         float* __restrict__ Mout, float* __restrict__ numpart,
                         float* __restrict__ cntpart, float* __restrict__ out0) {
  const int bp = blockIdx.x;
  const int b  = bp >> 4;       // NCHUNK == 16
  const int p  = bp & 15;
  const int tid = threadIdx.x;
  if (bp == 0 && tid == 0) out0[0] = 0.f;   // zero loss accumulator for k_final
  const int g = tid >> 4;
  const int k = tid & 15;
  const int kk = (k < 13) ? k : 0;
  const int gg = (g < 13) ? g : 0;
  const bool active = (g < 13) && (k < 13);
  const size_t lbase = (size_t)b * Sc;
  const int t0 = 1 + p * CHUNK;
  const int t1 = min(t0 + CHUNK, Sc);

  float U[13];   // column kk of exp(T)
#pragma unroll
  for (int j = 0; j < 13; ++j) U[j] = EXP2F(T[j * 13 + kk] * INV_LN2);

  float e0 = logits[(lbase + t0) * Lc + kk] * INV_LN2;
  int   m0 = mask[lbase + t0];
  float P = m0 ? EXP2F(T[gg * 13 + kk] * INV_LN2 + e0) : ((g == k) ? 1.f : 0.f);
  float off = 0.f;

  for (int t = t0 + 1; t < t1; ++t) {
    float e2 = logits[(lbase + t) * Lc + kk] * INV_LN2;
    int   mk = mask[lbase + t];
    float pj[13];
#pragma unroll
    for (int j = 0; j < 13; ++j) pj[j] = __shfl(P, j, 16);
    float s0 = pj[0] * U[0];  s0 = fmaf(pj[4],  U[4],  s0);
    s0 = fmaf(pj[8],  U[8],  s0);  s0 = fmaf(pj[12], U[12], s0);
    float s1 = pj[1] * U[1];  s1 = fmaf(pj[5],  U[5],  s1);  s1 = fmaf(pj[9],  U[9],  s1);
    float s2 = pj[2] * U[2];  s2 = fmaf(pj[6],  U[6],  s2);  s2 = fmaf(pj[10], U[10], s2);
    float s3 = pj[3] * U[3];  s3 = fmaf(pj[7],  U[7],  s3);  s3 = fmaf(pj[11], U[11], s3);
    float s = (s0 + s1) + (s2 + s3);
    float Pn = EXP2F(e2) * s;
    P = mk ? Pn : P;
    if (((t - t0) & 7) == 0) {   // renorm: keep row max in [1,2)
      float mx = P;
#pragma unroll
      for (int o = 1; o < 16; o <<= 1) mx = fmaxf(mx, __shfl_xor(mx, o, 16));
      unsigned eb = (__float_as_uint(mx) >> 23) & 255u;
      float scale = __uint_as_float((254u - eb) << 23);   // 2^(127-eb)
      P *= scale;
      off += (float)((int)eb - 127);
    }
  }
  if (active) Mout[(size_t)bp * 169 + g * 13 + k] = (P > 0.f) ? (LOG2F(P) + off) : -1e30f;

  // ---- numerator partial for this chunk's tokens [t0, t1) ----
  if (tid < 64) {
    float np = 0.f; int cnt = 0;
    for (int t = t0 + tid; t < t1; t += 64) {
      int mk = mask[lbase + t];
      if (mk) {
        int tg = labels[lbase + t];
        int pg = labels[lbase + t - 1];
        np += T[pg * 13 + tg] + logits[(lbase + t) * Lc + tg];
        cnt += 1;
      }
    }
#pragma unroll
    for (int o = 1; o < 64; o <<= 1) {
      np  += __shfl_xor(np, o, 64);
      cnt += __shfl_xor(cnt, o, 64);
    }
    if (tid == 0) { numpart[bp] = np; cntpart[bp] = (float)cnt; }
  }
}

// ---------------------------------------------------------------------------
// Kernel C: per batch: combine 16 chunk matrices (log2 domain) -> denominator;
// assemble numerator from partials; atomicAdd loss.
// ---------------------------------------------------------------------------
__global__ void k_final(const float* __restrict__ logits, const int* __restrict__ mask,
                        const int* __restrict__ labels, const float* __restrict__ startT,
                        const float* __restrict__ endT, const float* __restrict__ Mws,
                        const float* __restrict__ numpart, const float* __restrict__ cntpart,
                        float* __restrict__ out0) {
  const int b = blockIdx.x;
  const int lane = threadIdx.x;
  const int kk = (lane < 13) ? lane : 0;
  const size_t lbase = (size_t)b * Sc;

  // ---- denominator (log2 domain) ----
  float v = (startT[kk] + logits[lbase * Lc + kk]) * INV_LN2;
  for (int p = 0; p < NCHUNK; ++p) {
    const float* Mp = Mws + (size_t)(b * NCHUNK + p) * 169;
    float a[13];
#pragma unroll
    for (int j = 0; j < 13; ++j) a[j] = __shfl(v, j, 64) + Mp[j * 13 + kk];
    float mx = a[0];
#pragma unroll
    for (int j = 1; j < 13; ++j) mx = fmaxf(mx, a[j]);
    float s = 0.f;
#pragma unroll
    for (int j = 0; j < 13; ++j) s += EXP2F(a[j] - mx);
    v = mx + LOG2F(s);
  }
  float x = (lane < 13) ? (v + endT[kk] * INV_LN2) : -1e30f;
  float mx = x;
#pragma unroll
  for (int off = 1; off < 16; off <<= 1) mx = fmaxf(mx, __shfl_xor(mx, off, 16));
  float sx = EXP2F(x - mx);
#pragma unroll
  for (int off = 1; off < 16; off <<= 1) sx += __shfl_xor(sx, off, 16);
  float den = (mx + LOG2F(sx)) * LN2f;   // valid on lanes 0..15

  // ---- numerator from chunk partials (lanes 0..15) ----
  float np = 0.f, cs = 0.f;
  if (lane < NCHUNK) { np = numpart[b * NCHUNK + lane]; cs = cntpart[b * NCHUNK + lane]; }
#pragma unroll
  for (int o = 1; o < 16; o <<= 1) {
    np += __shfl_xor(np, o, 16);
    cs += __shfl_xor(cs, o, 16);
  }
  if (lane == 0) {
    int lab0 = labels[lbase];
    int seqlen = mask[lbase] + (int)(cs + 0.5f);
    int lastTag = labels[lbase + seqlen - 1];
    float num = startT[lab0] + logits[lbase * Lc + lab0] + np + endT[lastTag];
    float llh = num - den;
    atomicAdd(out0, -llh * (1.0f / Bc));
  }
}

extern "C" void kernel_launch(void* const* d_in, const int* in_sizes, int n_in,
                              void* d_out, int out_size, void* d_ws, size_t ws_size,
                              hipStream_t stream) {
  const float* hs     = (const float*)d_in[0];
  const int*   amask  = (const int*)d_in[1];
  const int*   labels = (const int*)d_in[2];
  const float* W      = (const float*)d_in[3];
  const float* bias   = (const float*)d_in[4];
  const float* startT = (const float*)d_in[5];
  const float* endT   = (const float*)d_in[6];
  const float* T      = (const float*)d_in[7];

  float* out    = (float*)d_out;
  float* logits = out + 1;            // output 1 follows the scalar loss
  float* Mws    = (float*)d_ws;       // 512*169 floats = 346 KB
  float* numpart = Mws + (size_t)NBLK * 169;
  float* cntpart = numpart + NBLK;    // total ~350 KB of ws

  k_logits<<<BSc / 64, 512, 0, stream>>>(hs, W, bias, logits);
  k_chunks<<<NBLK, 256, 0, stream>>>(logits, amask, labels, T, Mws, numpart, cntpart, out);
  k_final <<<Bc, 64, 0, stream>>>(logits, amask, labels, startT, endT, Mws, numpart, cntpart, out);
}

// Round 8
// 116.095 us; speedup vs baseline: 3.2728x; 1.4895x over previous
//
#include <hip/hip_runtime.h>
#include <math.h>

#define Lc 13
#define Hc 1024
#define Bc 32
#define Sc 2048
#define BSc (Bc*Sc)
#define CHUNK 128
#define NCHUNK 16
#define NBLK (Bc*NCHUNK)   // 512 chunk blocks

#define INV_LN2 1.44269504088896340736f
#define LN2f    0.69314718055994530942f

#if __has_builtin(__builtin_amdgcn_exp2f)
#define EXP2F(x) __builtin_amdgcn_exp2f(x)
#else
#define EXP2F(x) exp2f(x)
#endif
#if __has_builtin(__builtin_amdgcn_logf)
#define LOG2F(x) __builtin_amdgcn_logf(x)
#else
#define LOG2F(x) log2f(x)
#endif

// DPP-based partial butterfly: v += lane-permuted v (VALU only, no LDS).
template <int CTRL>
__device__ __forceinline__ float dpp_add(float v) {
  int p = __builtin_amdgcn_update_dpp(0, __float_as_int(v), CTRL, 0xF, 0xF, true);
  return v + __int_as_float(p);
}

__device__ __forceinline__ void load2(const float* __restrict__ A, size_t r0, int ln,
                                      float4 a0[4], float4 a1[4]) {
  const float* A0 = A + r0 * Hc + ln * 4;
  const float* A1 = A0 + Hc;
#pragma unroll
  for (int k = 0; k < 4; ++k) {
    a0[k] = *(const float4*)(A0 + k * 256);
    a1[k] = *(const float4*)(A1 + k * 256);
  }
}

// ---------------------------------------------------------------------------
// Kernel A: logits = hs @ W^T + b, barrier-free streaming + register-level
// A prefetch (issue-early / consume-late): iter-0 loads issued BEFORE the
// W-stage barrier; each iter issues iter+1's loads before computing, so the
// ~900cyc HBM latency hides under ~1000cyc of FMA+LDS work (R7 was
// latency-bound: 1.25 TB/s, VALU 22%, occ 21%). Ping-pong bufs, static
// indexing only (full unroll). (512,2): 128 VGPR, no spill (R6 lesson).
// ---------------------------------------------------------------------------
__global__ __launch_bounds__(512, 2)
void k_logits(const float* __restrict__ A, const float* __restrict__ W,
              const float* __restrict__ bias, float* __restrict__ out) {
  __shared__ float Wl[Lc * Hc];   // 53.2 KB
  const int tid = threadIdx.x;
  const int ln = tid & 63;
  const int wv = tid >> 6;                       // 0..7
  const size_t rowBase = (size_t)blockIdx.x * 64 + (size_t)wv * 8;

  float4 pa0[4], pa1[4], qa0[4], qa1[4];
  load2(A, rowBase, ln, pa0, pa1);               // prefetch iter 0 (pre-barrier)

  { // stage W once, coalesced float4
    const float4* Wg4 = (const float4*)W;
    float4* Wl4 = (float4*)Wl;
#pragma unroll
    for (int i = 0; i < 7; ++i) {
      int idx = tid + i * 512;
      if (idx < Lc * (Hc / 4)) Wl4[idx] = Wg4[idx];
    }
  }
  __syncthreads();

  float b[Lc];
#pragma unroll
  for (int l = 0; l < Lc; ++l) b[l] = bias[l];   // uniform -> SGPR

#pragma unroll
  for (int it = 0; it < 4; ++it) {
    const size_t r0 = rowBase + 2 * (size_t)it;
    // consume buffer (static select under full unroll)
    float4 a0[4], a1[4];
#pragma unroll
    for (int k = 0; k < 4; ++k) {
      a0[k] = ((it & 1) == 0) ? pa0[k] : qa0[k];
      a1[k] = ((it & 1) == 0) ? pa1[k] : qa1[k];
    }
    // issue next iter's loads before computing this one
    if (it < 3) {
      if ((it & 1) == 0) load2(A, r0 + 2, ln, qa0, qa1);
      else               load2(A, r0 + 2, ln, pa0, pa1);
    }

    float acc0[Lc], acc1[Lc];
#pragma unroll
    for (int l = 0; l < Lc; ++l) { acc0[l] = 0.f; acc1[l] = 0.f; }
#pragma unroll
    for (int l = 0; l < Lc; ++l) {
#pragma unroll
      for (int k = 0; k < 4; ++k) {
        float4 w = *(const float4*)&Wl[l * Hc + k * 256 + ln * 4];
        acc0[l] = fmaf(a0[k].x, w.x, acc0[l]); acc0[l] = fmaf(a0[k].y, w.y, acc0[l]);
        acc0[l] = fmaf(a0[k].z, w.z, acc0[l]); acc0[l] = fmaf(a0[k].w, w.w, acc0[l]);
        acc1[l] = fmaf(a1[k].x, w.x, acc1[l]); acc1[l] = fmaf(a1[k].y, w.y, acc1[l]);
        acc1[l] = fmaf(a1[k].z, w.z, acc1[l]); acc1[l] = fmaf(a1[k].w, w.w, acc1[l]);
      }
    }
    // 64-lane butterfly on 26 values.
    // quad_perm(1,0,3,2)=0xB1; quad_perm(2,3,0,1)=0x4E;
    // row_half_mirror=0x141; row_mirror=0x140.
#pragma unroll
    for (int l = 0; l < Lc; ++l) {
      float s0 = acc0[l], s1 = acc1[l];
      s0 = dpp_add<0xB1>(s0);  s1 = dpp_add<0xB1>(s1);
      s0 = dpp_add<0x4E>(s0);  s1 = dpp_add<0x4E>(s1);
      s0 = dpp_add<0x141>(s0); s1 = dpp_add<0x141>(s1);
      s0 = dpp_add<0x140>(s0); s1 = dpp_add<0x140>(s1);
      s0 += __shfl_xor(s0, 16, 64); s1 += __shfl_xor(s1, 16, 64);
      s0 += __shfl_xor(s0, 32, 64); s1 += __shfl_xor(s1, 32, 64);
      acc0[l] = s0; acc1[l] = s1;
    }
    float ov = 0.f;
#pragma unroll
    for (int l = 0; l < Lc; ++l) {
      ov = (ln == l)      ? acc0[l] + b[l] : ov;
      ov = (ln == Lc + l) ? acc1[l] + b[l] : ov;
    }
    if (ln < 2 * Lc) out[r0 * Lc + ln] = ov;
  }
}

// ---------------------------------------------------------------------------
// Kernel B: per (batch, chunk) 13x13 transfer matrix, LINEAR domain
// (13 shfl + 13 fma + 1 exp2 per step; exponent-extract renorm every 8).
// Wave 0 also computes the chunk's numerator partial. Block 0 zeroes out0.
// ---------------------------------------------------------------------------
__global__ void k_chunks(const float* __restrict__ logits, const int* __restrict__ mask,
                         const int* __restrict__ labels, const float* __restrict__ T,
                         float* __restrict__ Mout, float* __restrict__ numpart,
                         float* __restrict__ cntpart, float* __restrict__ out0) {
  const int bp = blockIdx.x;
  const int b  = bp >> 4;       // NCHUNK == 16
  const int p  = bp & 15;
  const int tid = threadIdx.x;
  if (bp == 0 && tid == 0) out0[0] = 0.f;   // zero loss accumulator for k_final
  const int g = tid >> 4;
  const int k = tid & 15;
  const int kk = (k < 13) ? k : 0;
  const int gg = (g < 13) ? g : 0;
  const bool active = (g < 13) && (k < 13);
  const size_t lbase = (size_t)b * Sc;
  const int t0 = 1 + p * CHUNK;
  const int t1 = min(t0 + CHUNK, Sc);

  float U[13];   // column kk of exp(T)
#pragma unroll
  for (int j = 0; j < 13; ++j) U[j] = EXP2F(T[j * 13 + kk] * INV_LN2);

  float e0 = logits[(lbase + t0) * Lc + kk] * INV_LN2;
  int   m0 = mask[lbase + t0];
  float P = m0 ? EXP2F(T[gg * 13 + kk] * INV_LN2 + e0) : ((g == k) ? 1.f : 0.f);
  float off = 0.f;

  for (int t = t0 + 1; t < t1; ++t) {
    float e2 = logits[(lbase + t) * Lc + kk] * INV_LN2;
    int   mk = mask[lbase + t];
    float pj[13];
#pragma unroll
    for (int j = 0; j < 13; ++j) pj[j] = __shfl(P, j, 16);
    float s0 = pj[0] * U[0];  s0 = fmaf(pj[4],  U[4],  s0);
    s0 = fmaf(pj[8],  U[8],  s0);  s0 = fmaf(pj[12], U[12], s0);
    float s1 = pj[1] * U[1];  s1 = fmaf(pj[5],  U[5],  s1);  s1 = fmaf(pj[9],  U[9],  s1);
    float s2 = pj[2] * U[2];  s2 = fmaf(pj[6],  U[6],  s2);  s2 = fmaf(pj[10], U[10], s2);
    float s3 = pj[3] * U[3];  s3 = fmaf(pj[7],  U[7],  s3);  s3 = fmaf(pj[11], U[11], s3);
    float s = (s0 + s1) + (s2 + s3);
    float Pn = EXP2F(e2) * s;
    P = mk ? Pn : P;
    if (((t - t0) & 7) == 0) {   // renorm: keep row max in [1,2)
      float mx = P;
#pragma unroll
      for (int o = 1; o < 16; o <<= 1) mx = fmaxf(mx, __shfl_xor(mx, o, 16));
      unsigned eb = (__float_as_uint(mx) >> 23) & 255u;
      float scale = __uint_as_float((254u - eb) << 23);   // 2^(127-eb)
      P *= scale;
      off += (float)((int)eb - 127);
    }
  }
  if (active) Mout[(size_t)bp * 169 + g * 13 + k] = (P > 0.f) ? (LOG2F(P) + off) : -1e30f;

  // ---- numerator partial for this chunk's tokens [t0, t1) ----
  if (tid < 64) {
    float np = 0.f; int cnt = 0;
    for (int t = t0 + tid; t < t1; t += 64) {
      int mk = mask[lbase + t];
      if (mk) {
        int tg = labels[lbase + t];
        int pg = labels[lbase + t - 1];
        np += T[pg * 13 + tg] + logits[(lbase + t) * Lc + tg];
        cnt += 1;
      }
    }
#pragma unroll
    for (int o = 1; o < 64; o <<= 1) {
      np  += __shfl_xor(np, o, 64);
      cnt += __shfl_xor(cnt, o, 64);
    }
    if (tid == 0) { numpart[bp] = np; cntpart[bp] = (float)cnt; }
  }
}

// ---------------------------------------------------------------------------
// Kernel C: per batch: combine 16 chunk matrices (log2 domain) -> denominator;
// assemble numerator from partials; atomicAdd loss.
// ---------------------------------------------------------------------------
__global__ void k_final(const float* __restrict__ logits, const int* __restrict__ mask,
                        const int* __restrict__ labels, const float* __restrict__ startT,
                        const float* __restrict__ endT, const float* __restrict__ Mws,
                        const float* __restrict__ numpart, const float* __restrict__ cntpart,
                        float* __restrict__ out0) {
  const int b = blockIdx.x;
  const int lane = threadIdx.x;
  const int kk = (lane < 13) ? lane : 0;
  const size_t lbase = (size_t)b * Sc;

  // ---- denominator (log2 domain) ----
  float v = (startT[kk] + logits[lbase * Lc + kk]) * INV_LN2;
  for (int p = 0; p < NCHUNK; ++p) {
    const float* Mp = Mws + (size_t)(b * NCHUNK + p) * 169;
    float a[13];
#pragma unroll
    for (int j = 0; j < 13; ++j) a[j] = __shfl(v, j, 64) + Mp[j * 13 + kk];
    float mx = a[0];
#pragma unroll
    for (int j = 1; j < 13; ++j) mx = fmaxf(mx, a[j]);
    float s = 0.f;
#pragma unroll
    for (int j = 0; j < 13; ++j) s += EXP2F(a[j] - mx);
    v = mx + LOG2F(s);
  }
  float x = (lane < 13) ? (v + endT[kk] * INV_LN2) : -1e30f;
  float mx = x;
#pragma unroll
  for (int off = 1; off < 16; off <<= 1) mx = fmaxf(mx, __shfl_xor(mx, off, 16));
  float sx = EXP2F(x - mx);
#pragma unroll
  for (int off = 1; off < 16; off <<= 1) sx += __shfl_xor(sx, off, 16);
  float den = (mx + LOG2F(sx)) * LN2f;   // valid on lanes 0..15

  // ---- numerator from chunk partials (lanes 0..15) ----
  float np = 0.f, cs = 0.f;
  if (lane < NCHUNK) { np = numpart[b * NCHUNK + lane]; cs = cntpart[b * NCHUNK + lane]; }
#pragma unroll
  for (int o = 1; o < 16; o <<= 1) {
    np += __shfl_xor(np, o, 16);
    cs += __shfl_xor(cs, o, 16);
  }
  if (lane == 0) {
    int lab0 = labels[lbase];
    int seqlen = mask[lbase] + (int)(cs + 0.5f);
    int lastTag = labels[lbase + seqlen - 1];
    float num = startT[lab0] + logits[lbase * Lc + lab0] + np + endT[lastTag];
    float llh = num - den;
    atomicAdd(out0, -llh * (1.0f / Bc));
  }
}

extern "C" void kernel_launch(void* const* d_in, const int* in_sizes, int n_in,
                              void* d_out, int out_size, void* d_ws, size_t ws_size,
                              hipStream_t stream) {
  const float* hs     = (const float*)d_in[0];
  const int*   amask  = (const int*)d_in[1];
  const int*   labels = (const int*)d_in[2];
  const float* W      = (const float*)d_in[3];
  const float* bias   = (const float*)d_in[4];
  const float* startT = (const float*)d_in[5];
  const float* endT   = (const float*)d_in[6];
  const float* T      = (const float*)d_in[7];

  float* out    = (float*)d_out;
  float* logits = out + 1;            // output 1 follows the scalar loss
  float* Mws    = (float*)d_ws;       // 512*169 floats = 346 KB
  float* numpart = Mws + (size_t)NBLK * 169;
  float* cntpart = numpart + NBLK;    // total ~350 KB of ws

  k_logits<<<BSc / 64, 512, 0, stream>>>(hs, W, bias, logits);
  k_chunks<<<NBLK, 256, 0, stream>>>(logits, amask, labels, T, Mws, numpart, cntpart, out);
  k_final <<<Bc, 64, 0, stream>>>(logits, amask, labels, startT, endT, Mws, numpart, cntpart, out);
}

// Round 10
// 103.885 us; speedup vs baseline: 3.6574x; 1.1175x over previous
//
#include <hip/hip_runtime.h>
#include <math.h>

#define Lc 13
#define Hc 1024
#define Bc 32
#define Sc 2048
#define BSc (Bc*Sc)
#define CHUNK 128
#define NCHUNK 16
#define NBLK (Bc*NCHUNK)   // 512 chunk blocks

#define INV_LN2 1.44269504088896340736f
#define LN2f    0.69314718055994530942f

#if __has_builtin(__builtin_amdgcn_exp2f)
#define EXP2F(x) __builtin_amdgcn_exp2f(x)
#else
#define EXP2F(x) exp2f(x)
#endif
#if __has_builtin(__builtin_amdgcn_logf)
#define LOG2F(x) __builtin_amdgcn_logf(x)
#else
#define LOG2F(x) log2f(x)
#endif

// DPP-based partial butterfly: v += lane-permuted v (VALU only, no LDS).
template <int CTRL>
__device__ __forceinline__ float dpp_add(float v) {
  int p = __builtin_amdgcn_update_dpp(0, __float_as_int(v), CTRL, 0xF, 0xF, true);
  return v + __int_as_float(p);
}

// ---------------------------------------------------------------------------
// Kernel A: logits = hs @ W^T + b.  Lane->(row, chunk): lane = rin*16+ch,
// rows rowBase+rin (g=0) and rowBase+4+rin (g=1). Slice kk covers
// h = kk*64 + ch*4 .. +3; SIXTEEN slices cover all 1024 h (R9 bug: 4 slices
// strided 256 covered only 256 h -> absmax 288). Per slice: 2 A-loads,
// 13 ds_read_b128 (shared by g=0/1, broadcast to 4 rin groups), 104 FMA.
// 3-slot rotating A buffer, depth-2 prefetch, static indices (full unroll).
// Reduction within 16-lane groups = pure DPP (validated in R7/R8).
// (512,6): 6 waves/SIMD, 3 blocks/CU (3x53.2KB = 159.7KB LDS), ~70 VGPR.
// ---------------------------------------------------------------------------
__global__ __launch_bounds__(512, 6)
void k_logits(const float* __restrict__ A, const float* __restrict__ W,
              const float* __restrict__ bias, float* __restrict__ out) {
  __shared__ float Wl[Lc * Hc];   // 53.2 KB
  const int tid = threadIdx.x;
  const int ln  = tid & 63;
  const int wv  = tid >> 6;            // 0..7
  const int rin = ln >> 4;             // row within 4-row group
  const int ch  = ln & 15;             // 16B chunk within 64-float slice
  const size_t rowBase = (size_t)blockIdx.x * 64 + (size_t)wv * 8;

  const float* A0 = A + (rowBase + rin) * (size_t)Hc + ch * 4;  // g=0 row
  const float* A1 = A0 + 4 * (size_t)Hc;                        // g=1 row

  // ---- depth-2 prefetch: slices 0,1 issued before the W-stage barrier ----
  float4 buf0[2], buf1[2];   // [slot = kk % 3 handled via 3 named pairs]
  float4 buf0c, buf1c;       // slot 2
  buf0[0] = *(const float4*)(A0);        buf1[0] = *(const float4*)(A1);
  buf0[1] = *(const float4*)(A0 + 64);   buf1[1] = *(const float4*)(A1 + 64);
  __builtin_amdgcn_sched_barrier(0);     // pin A prefetch before W-stage

  // ---- stage W once, coalesced float4 ----
  {
    const float4* Wg4 = (const float4*)W;
    float4* Wl4 = (float4*)Wl;
#pragma unroll
    for (int i = 0; i < 7; ++i) {
      int idx = tid + i * 512;
      if (idx < Lc * (Hc / 4)) Wl4[idx] = Wg4[idx];
    }
  }
  __syncthreads();

  float acc0[Lc], acc1[Lc];
#pragma unroll
  for (int l = 0; l < Lc; ++l) { acc0[l] = 0.f; acc1[l] = 0.f; }

#pragma unroll
  for (int kk = 0; kk < 16; ++kk) {
    // consume slot kk%3 (static under full unroll)
    float4 a0 = (kk % 3 == 0) ? buf0[0] : (kk % 3 == 1) ? buf0[1] : buf0c;
    float4 a1 = (kk % 3 == 0) ? buf1[0] : (kk % 3 == 1) ? buf1[1] : buf1c;
    // issue slice kk+2 into slot (kk+2)%3
    if (kk + 2 < 16) {
      float4 n0 = *(const float4*)(A0 + (kk + 2) * 64);
      float4 n1 = *(const float4*)(A1 + (kk + 2) * 64);
      if ((kk + 2) % 3 == 0)      { buf0[0] = n0; buf1[0] = n1; }
      else if ((kk + 2) % 3 == 1) { buf0[1] = n0; buf1[1] = n1; }
      else                        { buf0c   = n0; buf1c   = n1; }
    }
    const float* wb = &Wl[kk * 64 + ch * 4];
#pragma unroll
    for (int l = 0; l < Lc; ++l) {
      float4 w = *(const float4*)(wb + l * Hc);   // shared by g=0/1, bcast x4
      acc0[l] = fmaf(a0.x, w.x, acc0[l]); acc0[l] = fmaf(a0.y, w.y, acc0[l]);
      acc0[l] = fmaf(a0.z, w.z, acc0[l]); acc0[l] = fmaf(a0.w, w.w, acc0[l]);
      acc1[l] = fmaf(a1.x, w.x, acc1[l]); acc1[l] = fmaf(a1.y, w.y, acc1[l]);
      acc1[l] = fmaf(a1.z, w.z, acc1[l]); acc1[l] = fmaf(a1.w, w.w, acc1[l]);
    }
  }

  // reduce within 16-lane group: xor1,xor2 (quad_perm), ^7, ^15 (mirrors)
#pragma unroll
  for (int l = 0; l < Lc; ++l) {
    float s0 = acc0[l], s1 = acc1[l];
    s0 = dpp_add<0xB1>(s0);   s1 = dpp_add<0xB1>(s1);
    s0 = dpp_add<0x4E>(s0);   s1 = dpp_add<0x4E>(s1);
    s0 = dpp_add<0x141>(s0);  s1 = dpp_add<0x141>(s1);
    s0 = dpp_add<0x140>(s0);  s1 = dpp_add<0x140>(s1);
    acc0[l] = s0; acc1[l] = s1;
  }
  float ov0 = 0.f, ov1 = 0.f;
#pragma unroll
  for (int l = 0; l < Lc; ++l) {
    float bl = bias[l];
    ov0 = (ch == l) ? acc0[l] + bl : ov0;
    ov1 = (ch == l) ? acc1[l] + bl : ov1;
  }
  if (ch < Lc) {
    out[(rowBase + rin) * Lc + ch]     = ov0;
    out[(rowBase + 4 + rin) * Lc + ch] = ov1;
  }
}

// ---------------------------------------------------------------------------
// Kernel B: per (batch, chunk) 13x13 transfer matrix, LINEAR domain
// (13 shfl + 13 fma + 1 exp2 per step; exponent-extract renorm every 8).
// Wave 0 also computes the chunk's numerator partial. Block 0 zeroes out0.
// ---------------------------------------------------------------------------
__global__ void k_chunks(const float* __restrict__ logits, const int* __restrict__ mask,
                         const int* __restrict__ labels, const float* __restrict__ T,
                         float* __restrict__ Mout, float* __restrict__ numpart,
                         float* __restrict__ cntpart, float* __restrict__ out0) {
  const int bp = blockIdx.x;
  const int b  = bp >> 4;       // NCHUNK == 16
  const int p  = bp & 15;
  const int tid = threadIdx.x;
  if (bp == 0 && tid == 0) out0[0] = 0.f;   // zero loss accumulator for k_final
  const int g = tid >> 4;
  const int k = tid & 15;
  const int kk = (k < 13) ? k : 0;
  const int gg = (g < 13) ? g : 0;
  const bool active = (g < 13) && (k < 13);
  const size_t lbase = (size_t)b * Sc;
  const int t0 = 1 + p * CHUNK;
  const int t1 = min(t0 + CHUNK, Sc);

  float U[13];   // column kk of exp(T)
#pragma unroll
  for (int j = 0; j < 13; ++j) U[j] = EXP2F(T[j * 13 + kk] * INV_LN2);

  float e0 = logits[(lbase + t0) * Lc + kk] * INV_LN2;
  int   m0 = mask[lbase + t0];
  float P = m0 ? EXP2F(T[gg * 13 + kk] * INV_LN2 + e0) : ((g == k) ? 1.f : 0.f);
  float off = 0.f;

  for (int t = t0 + 1; t < t1; ++t) {
    float e2 = logits[(lbase + t) * Lc + kk] * INV_LN2;
    int   mk = mask[lbase + t];
    float pj[13];
#pragma unroll
    for (int j = 0; j < 13; ++j) pj[j] = __shfl(P, j, 16);
    float s0 = pj[0] * U[0];  s0 = fmaf(pj[4],  U[4],  s0);
    s0 = fmaf(pj[8],  U[8],  s0);  s0 = fmaf(pj[12], U[12], s0);
    float s1 = pj[1] * U[1];  s1 = fmaf(pj[5],  U[5],  s1);  s1 = fmaf(pj[9],  U[9],  s1);
    float s2 = pj[2] * U[2];  s2 = fmaf(pj[6],  U[6],  s2);  s2 = fmaf(pj[10], U[10], s2);
    float s3 = pj[3] * U[3];  s3 = fmaf(pj[7],  U[7],  s3);  s3 = fmaf(pj[11], U[11], s3);
    float s = (s0 + s1) + (s2 + s3);
    float Pn = EXP2F(e2) * s;
    P = mk ? Pn : P;
    if (((t - t0) & 7) == 0) {   // renorm: keep row max in [1,2)
      float mx = P;
#pragma unroll
      for (int o = 1; o < 16; o <<= 1) mx = fmaxf(mx, __shfl_xor(mx, o, 16));
      unsigned eb = (__float_as_uint(mx) >> 23) & 255u;
      float scale = __uint_as_float((254u - eb) << 23);   // 2^(127-eb)
      P *= scale;
      off += (float)((int)eb - 127);
    }
  }
  if (active) Mout[(size_t)bp * 169 + g * 13 + k] = (P > 0.f) ? (LOG2F(P) + off) : -1e30f;

  // ---- numerator partial for this chunk's tokens [t0, t1) ----
  if (tid < 64) {
    float np = 0.f; int cnt = 0;
    for (int t = t0 + tid; t < t1; t += 64) {
      int mk = mask[lbase + t];
      if (mk) {
        int tg = labels[lbase + t];
        int pg = labels[lbase + t - 1];
        np += T[pg * 13 + tg] + logits[(lbase + t) * Lc + tg];
        cnt += 1;
      }
    }
#pragma unroll
    for (int o = 1; o < 64; o <<= 1) {
      np  += __shfl_xor(np, o, 64);
      cnt += __shfl_xor(cnt, o, 64);
    }
    if (tid == 0) { numpart[bp] = np; cntpart[bp] = (float)cnt; }
  }
}

// ---------------------------------------------------------------------------
// Kernel C: per batch: combine 16 chunk matrices (log2 domain) -> denominator;
// assemble numerator from partials; atomicAdd loss.
// ---------------------------------------------------------------------------
__global__ void k_final(const float* __restrict__ logits, const int* __restrict__ mask,
                        const int* __restrict__ labels, const float* __restrict__ startT,
                        const float* __restrict__ endT, const float* __restrict__ Mws,
                        const float* __restrict__ numpart, const float* __restrict__ cntpart,
                        float* __restrict__ out0) {
  const int b = blockIdx.x;
  const int lane = threadIdx.x;
  const int kk = (lane < 13) ? lane : 0;
  const size_t lbase = (size_t)b * Sc;

  // ---- denominator (log2 domain) ----
  float v = (startT[kk] + logits[lbase * Lc + kk]) * INV_LN2;
  for (int p = 0; p < NCHUNK; ++p) {
    const float* Mp = Mws + (size_t)(b * NCHUNK + p) * 169;
    float a[13];
#pragma unroll
    for (int j = 0; j < 13; ++j) a[j] = __shfl(v, j, 64) + Mp[j * 13 + kk];
    float mx = a[0];
#pragma unroll
    for (int j = 1; j < 13; ++j) mx = fmaxf(mx, a[j]);
    float s = 0.f;
#pragma unroll
    for (int j = 0; j < 13; ++j) s += EXP2F(a[j] - mx);
    v = mx + LOG2F(s);
  }
  float x = (lane < 13) ? (v + endT[kk] * INV_LN2) : -1e30f;
  float mx = x;
#pragma unroll
  for (int off = 1; off < 16; off <<= 1) mx = fmaxf(mx, __shfl_xor(mx, off, 16));
  float sx = EXP2F(x - mx);
#pragma unroll
  for (int off = 1; off < 16; off <<= 1) sx += __shfl_xor(sx, off, 16);
  float den = (mx + LOG2F(sx)) * LN2f;   // valid on lanes 0..15

  // ---- numerator from chunk partials (lanes 0..15) ----
  float np = 0.f, cs = 0.f;
  if (lane < NCHUNK) { np = numpart[b * NCHUNK + lane]; cs = cntpart[b * NCHUNK + lane]; }
#pragma unroll
  for (int o = 1; o < 16; o <<= 1) {
    np += __shfl_xor(np, o, 16);
    cs += __shfl_xor(cs, o, 16);
  }
  if (lane == 0) {
    int lab0 = labels[lbase];
    int seqlen = mask[lbase] + (int)(cs + 0.5f);
    int lastTag = labels[lbase + seqlen - 1];
    float num = startT[lab0] + logits[lbase * Lc + lab0] + np + endT[lastTag];
    float llh = num - den;
    atomicAdd(out0, -llh * (1.0f / Bc));
  }
}

extern "C" void kernel_launch(void* const* d_in, const int* in_sizes, int n_in,
                              void* d_out, int out_size, void* d_ws, size_t ws_size,
                              hipStream_t stream) {
  const float* hs     = (const float*)d_in[0];
  const int*   amask  = (const int*)d_in[1];
  const int*   labels = (const int*)d_in[2];
  const float* W      = (const float*)d_in[3];
  const float* bias   = (const float*)d_in[4];
  const float* startT = (const float*)d_in[5];
  const float* endT   = (const float*)d_in[6];
  const float* T      = (const float*)d_in[7];

  float* out    = (float*)d_out;
  float* logits = out + 1;            // output 1 follows the scalar loss
  float* Mws    = (float*)d_ws;       // 512*169 floats = 346 KB
  float* numpart = Mws + (size_t)NBLK * 169;
  float* cntpart = numpart + NBLK;    // total ~350 KB of ws

  k_logits<<<BSc / 64, 512, 0, stream>>>(hs, W, bias, logits);
  k_chunks<<<NBLK, 256, 0, stream>>>(logits, amask, labels, T, Mws, numpart, cntpart, out);
  k_final <<<Bc, 64, 0, stream>>>(logits, amask, labels, startT, endT, Mws, numpart, cntpart, out);
}